// Round 1
// baseline (94.250 us; speedup 1.0000x reference)
//
#include <hip/hip_runtime.h>

// JeffressFilter: T=1024, N=4, C=4 (NC=16 spatial channels, 2 in-features -> 32 scan channels),
// D_OUT=512 delay taps. decay = exp(-1/2).
//
// out[t,nc,d] = w[d] * ( [t>=dl0]*y[t-dl0, nc, 0] + [t>=dl1]*y[t-dl1, nc, 1] )
// where y is the leaky-integrator scan of x along t.
//
// Layouts (row-major, matching the reference):
//   x, y : [T, NC, 2]   flat = t*32 + nc*2 + i
//   out  : [T, NC, 512] flat = (t*16 + nc)*512 + d
//   delay: [512, 2] int32, weight: [512] float

#define T_LEN 1024
#define D_OUT 512

// ---------------------------------------------------------------------------
// Kernel 1: LIF scan into workspace y (32768 floats = 128 KB).
// 512 threads = 32 channels x 16 chunks of 64 timesteps, each with a 64-step
// warm-up from v=0 (truncation error ~ decay^64 = 1.3e-14, far below tol).
// ---------------------------------------------------------------------------
__global__ __launch_bounds__(512) void lif_scan_kernel(const float* __restrict__ x,
                                                       float* __restrict__ y) {
    const int tid   = threadIdx.x;
    const int ch    = tid & 31;   // scan channel: nc*2 + i
    const int chunk = tid >> 5;   // 0..15
    const int t0    = chunk * 64;
    const float decay = 0.60653065971263342f;  // exp(-0.5)

    float v = 0.0f;
    // warm-up: 64 steps before the chunk (predicated zero for t<0)
    #pragma unroll 8
    for (int k = 0; k < 64; ++k) {
        int t = t0 - 64 + k;
        float xv = (t >= 0) ? x[t * 32 + ch] : 0.0f;
        v = decay * v + xv;
    }
    // the chunk proper
    #pragma unroll 8
    for (int k = 0; k < 64; ++k) {
        int t = t0 + k;
        v = decay * v + x[t * 32 + ch];
        y[t * 32 + ch] = v;
    }
}

// ---------------------------------------------------------------------------
// Kernel 2: gather + mask + weight, float4-vectorized over d.
// One thread -> 4 consecutive d values -> one coalesced float4 store.
// 2,097,152 threads = 8192 blocks x 256.
// ---------------------------------------------------------------------------
__global__ __launch_bounds__(256) void jeffress_kernel(const float* __restrict__ y,
                                                       const float* __restrict__ w,
                                                       const int* __restrict__ delay,
                                                       float4* __restrict__ out) {
    const int f = blockIdx.x * blockDim.x + threadIdx.x;  // float4 index
    // f = (t*16 + nc)*128 + d4
    const int d4  = f & 127;
    const int tnc = f >> 7;
    const int nc  = tnc & 15;
    const int t   = tnc >> 4;
    const int d   = d4 * 4;

    // delay rows d..d+3: 8 contiguous ints
    const int4* dp = (const int4*)(delay + 2 * d);
    const int4 del01 = dp[0];  // (dl0_d, dl1_d, dl0_{d+1}, dl1_{d+1})
    const int4 del23 = dp[1];
    const float4 wv = ((const float4*)w)[d4];

    const float* yb = y + nc * 2;

    auto tap = [&](int dl0, int dl1) -> float {
        float a = (t >= dl0) ? yb[(t - dl0) * 32 + 0] : 0.0f;
        float b = (t >= dl1) ? yb[(t - dl1) * 32 + 1] : 0.0f;
        return a + b;
    };

    float4 o;
    o.x = wv.x * tap(del01.x, del01.y);
    o.y = wv.y * tap(del01.z, del01.w);
    o.z = wv.z * tap(del23.x, del23.y);
    o.w = wv.w * tap(del23.z, del23.w);
    out[f] = o;
}

extern "C" void kernel_launch(void* const* d_in, const int* in_sizes, int n_in,
                              void* d_out, int out_size, void* d_ws, size_t ws_size,
                              hipStream_t stream) {
    const float* x      = (const float*)d_in[0];   // (1024,4,4,2) fp32
    const float* weight = (const float*)d_in[1];   // (512,) fp32
    const int*   delay  = (const int*)d_in[2];     // (512,2) int32
    float* out = (float*)d_out;                    // (1024,4,4,512) fp32
    float* y   = (float*)d_ws;                     // 32768 floats scratch

    lif_scan_kernel<<<1, 512, 0, stream>>>(x, y);

    const int total4 = T_LEN * 16 * (D_OUT / 4);   // 2,097,152 float4 threads
    jeffress_kernel<<<total4 / 256, 256, 0, stream>>>(y, weight, delay, (float4*)out);
}

// Round 2
// 81.393 us; speedup vs baseline: 1.1580x; 1.1580x over previous
//
#include <hip/hip_runtime.h>

// JeffressFilter: T=1024, NC=16 spatial channels, 2 in-features, D_OUT=512 taps.
// out[t,nc,d] = w[d] * ( [t>=dl0]*y[t-dl0, nc, 0] + [t>=dl1]*y[t-dl1, nc, 1] )
// y = leaky-integrator scan of x (decay = exp(-1/2)).
//
// R2: LDS-staged gather. The global gather in R1 had lane-stride 128 B (one
// cache line per lane per tap) -> transaction-bound, 94 us. Here each block
// stages its 2.2 KB y-window into LDS; tap reads are broadcast or stride-1
// (conflict-free), and the t<delay mask becomes zero-padding of the window.

#define T_LEN  1024
#define D_OUT  512
#define T_TILE 16
#define WIN    (256 + T_TILE)   // 272: window t in [t0-256, t0+T_TILE)

// ---------------------------------------------------------------------------
// Kernel 1: LIF scan into workspace y (1024 x 32 floats = 128 KB).
// 512 threads = 32 channels x 16 chunks of 64 steps + 64-step warm-up
// (truncation error ~ decay^64 = 1.3e-14).
// ---------------------------------------------------------------------------
__global__ __launch_bounds__(512) void lif_scan_kernel(const float* __restrict__ x,
                                                       float* __restrict__ y) {
    const int tid   = threadIdx.x;
    const int ch    = tid & 31;   // nc*2 + i
    const int chunk = tid >> 5;   // 0..15
    const int t0    = chunk * 64;
    const float decay = 0.60653065971263342f;  // exp(-0.5)

    float v = 0.0f;
    #pragma unroll 8
    for (int k = 0; k < 64; ++k) {
        int t = t0 - 64 + k;
        float xv = (t >= 0) ? x[t * 32 + ch] : 0.0f;
        v = decay * v + xv;
    }
    #pragma unroll 8
    for (int k = 0; k < 64; ++k) {
        int t = t0 + k;
        v = decay * v + x[t * 32 + ch];
        y[t * 32 + ch] = v;
    }
}

// ---------------------------------------------------------------------------
// Kernel 2: per-block (t-tile x nc) LDS-staged gather + weight.
// Grid: (1024/T_TILE) * 16 = 1024 blocks x 256 threads.
// Thread -> d4 = tid&127 (4 consecutive d), t_half = tid>>7; 8 t's each.
// ---------------------------------------------------------------------------
__global__ __launch_bounds__(256) void jeffress_kernel(const float* __restrict__ y,
                                                       const float* __restrict__ w,
                                                       const int* __restrict__ delay,
                                                       float4* __restrict__ out) {
    __shared__ float y0[WIN];
    __shared__ float y1[WIN];

    const int bid = blockIdx.x;
    const int nc  = bid & 15;
    const int t0  = (bid >> 4) * T_TILE;
    const int tid = threadIdx.x;

    // Stage window: y_lds[i][k] = y[t0-256+k, nc, i], 0 if t<0 (implements mask).
    for (int k = tid; k < WIN; k += 256) {
        const int tg = t0 - 256 + k;
        float a = 0.0f, b = 0.0f;
        if (tg >= 0) {
            const float2 v = *(const float2*)(y + tg * 32 + nc * 2);
            a = v.x; b = v.y;
        }
        y0[k] = a;
        y1[k] = b;
    }
    __syncthreads();

    const int d4 = tid & 127;          // float4 index over d
    const int d  = d4 * 4;
    const int th = tid >> 7;           // 0 or 1

    const int4* dp = (const int4*)(delay + 2 * d);
    const int4 del01 = dp[0];          // (dl0_d, dl1_d, dl0_{d+1}, dl1_{d+1})
    const int4 del23 = dp[1];
    const float4 wv = ((const float4*)w)[d4];

    float4* outb = out + nc * (D_OUT / 4) + d4;

    #pragma unroll
    for (int j = 0; j < T_TILE / 2; ++j) {
        const int tl = th * (T_TILE / 2) + j;  // 0..15
        const int tr = 256 + tl;               // window-relative t
        float4 o;
        o.x = wv.x * (y0[tr - del01.x] + y1[tr - del01.y]);
        o.y = wv.y * (y0[tr - del01.z] + y1[tr - del01.w]);
        o.z = wv.z * (y0[tr - del23.x] + y1[tr - del23.y]);
        o.w = wv.w * (y0[tr - del23.z] + y1[tr - del23.w]);
        outb[(t0 + tl) * 16 * (D_OUT / 4)] = o;
    }
}

extern "C" void kernel_launch(void* const* d_in, const int* in_sizes, int n_in,
                              void* d_out, int out_size, void* d_ws, size_t ws_size,
                              hipStream_t stream) {
    const float* x      = (const float*)d_in[0];   // (1024,4,4,2) fp32
    const float* weight = (const float*)d_in[1];   // (512,) fp32
    const int*   delay  = (const int*)d_in[2];     // (512,2) int32
    float* out = (float*)d_out;                    // (1024,4,4,512) fp32
    float* y   = (float*)d_ws;                     // 32768 floats scratch

    lif_scan_kernel<<<1, 512, 0, stream>>>(x, y);

    const int nblocks = (T_LEN / T_TILE) * 16;     // 1024
    jeffress_kernel<<<nblocks, 256, 0, stream>>>(y, weight, delay, (float4*)out);
}

// Round 4
// 78.663 us; speedup vs baseline: 1.1981x; 1.0347x over previous
//
#include <hip/hip_runtime.h>

// JeffressFilter: T=1024, NC=16 spatial channels, 2 in-features, D_OUT=512 taps.
// out[t,nc,d] = w[d] * ( [t>=dl0]*y[t-dl0, nc, 0] + [t>=dl1]*y[t-dl1, nc, 1] )
// y = leaky-integrator scan of x (decay = exp(-1/2)).
//
// R4: R3 design with the scan-chunk bug fixed (R3 launched 32 chunk-slots for
// 16 chunks -> rows overran into neighboring pads/data). Layout:
//   ws: yA[nc][ROW], yB[nc][ROW]; ROW = 256(zero pad) + 1024(t), t contiguous.
// Gather reads y{A,B}[nc][PAD + t - dl]; dl<=256 so reads land in-row, pad
// supplies the t<delay zeros -> mask is free, no branches, no LDS.

#define T_LEN  1024
#define D_OUT  512
#define NC     16
#define PAD    256
#define ROW    (PAD + T_LEN)    // 1280 floats per row
#define YB_OFF (NC * ROW)       // second feature plane

// ---------------------------------------------------------------------------
// Kernel 1: zero the pads + LIF scan into transposed ws.
// 16 blocks x 64 threads. Block b: all threads zero a slice of the 32 pads;
// threads 0..31 scan chunk b (64 steps) for all 32 channels with a 64-step
// warm-up (truncation ~ exp(-32) = 1.3e-14).
// ---------------------------------------------------------------------------
__global__ __launch_bounds__(64) void lif_scan_kernel(const float* __restrict__ x,
                                                      float* __restrict__ ws) {
    const int tid = threadIdx.x;   // 0..63
    const int b   = blockIdx.x;    // 0..15 == chunk index

    // zero the 32 row-pads (32*256 = 8192 floats; 8 per thread)
    #pragma unroll
    for (int k = 0; k < 8; ++k) {
        const int id = (b * 64 + tid) * 8 + k;   // 0..8191
        const int r  = id >> 8;                  // row 0..31
        const int c  = id & 255;                 // pad col 0..255
        ws[r * ROW + c] = 0.0f;
    }

    if (tid < 32) {
        const int ch = tid;          // nc*2 + i
        const int nc = ch >> 1;
        const int i  = ch & 1;
        float* row = ws + (i ? YB_OFF : 0) + nc * ROW + PAD;

        const int   t0    = b * 64;
        const float decay = 0.60653065971263342f;  // exp(-0.5)

        float v = 0.0f;
        #pragma unroll 8
        for (int k = 0; k < 64; ++k) {
            const int t = t0 - 64 + k;
            const float xv = (t >= 0) ? x[t * 32 + ch] : 0.0f;
            v = decay * v + xv;
        }
        #pragma unroll 8
        for (int k = 0; k < 64; ++k) {
            const int t = t0 + k;
            v = decay * v + x[t * 32 + ch];
            row[t] = v;
        }
    }
}

// ---------------------------------------------------------------------------
// Kernel 2: branch-free gather + weight. 1024 blocks x 256 threads.
// Block = (t-tile of 16) x nc. Thread: d4 = tid&127 (4 consecutive d),
// th = tid>>7 selects 8 t's. 8 base pointers computed once; inner loop is
// 8 imm-offset loads (1 broadcast + contiguous group per tap class, all
// L1-hot) + 4 FMA + 1 coalesced float4 store per t.
// ---------------------------------------------------------------------------
__global__ __launch_bounds__(256) void jeffress_kernel(const float* __restrict__ ws,
                                                       const float* __restrict__ w,
                                                       const int* __restrict__ delay,
                                                       float4* __restrict__ out) {
    const int bid = blockIdx.x;
    const int nc  = bid & 15;
    const int t0  = (bid >> 4) * 16 + (threadIdx.x >> 7) * 8;
    const int d4  = threadIdx.x & 127;
    const int d   = d4 * 4;

    const int4*   dp  = (const int4*)(delay + 2 * d);
    const int4    e01 = dp[0];                 // (dl0_d, dl1_d, dl0_{d+1}, dl1_{d+1})
    const int4    e23 = dp[1];
    const float4  wv  = ((const float4*)w)[d4];

    const float* A = ws + nc * ROW + PAD + t0;
    const float* B = ws + YB_OFF + nc * ROW + PAD + t0;
    const float* a0 = A - e01.x;  const float* b0 = B - e01.y;
    const float* a1 = A - e01.z;  const float* b1 = B - e01.w;
    const float* a2 = A - e23.x;  const float* b2 = B - e23.y;
    const float* a3 = A - e23.z;  const float* b3 = B - e23.w;

    float4* op = out + (size_t)t0 * (NC * D_OUT / 4) + nc * (D_OUT / 4) + d4;

    #pragma unroll
    for (int j = 0; j < 8; ++j) {
        float4 o;
        o.x = wv.x * (a0[j] + b0[j]);
        o.y = wv.y * (a1[j] + b1[j]);
        o.z = wv.z * (a2[j] + b2[j]);
        o.w = wv.w * (a3[j] + b3[j]);
        op[j * (NC * D_OUT / 4)] = o;
    }
}

extern "C" void kernel_launch(void* const* d_in, const int* in_sizes, int n_in,
                              void* d_out, int out_size, void* d_ws, size_t ws_size,
                              hipStream_t stream) {
    const float* x      = (const float*)d_in[0];   // (1024,4,4,2) fp32
    const float* weight = (const float*)d_in[1];   // (512,) fp32
    const int*   delay  = (const int*)d_in[2];     // (512,2) int32
    float* out = (float*)d_out;                    // (1024,4,4,512) fp32
    float* ws  = (float*)d_ws;                     // 40960 floats used

    lif_scan_kernel<<<16, 64, 0, stream>>>(x, ws);

    const int nblocks = (T_LEN / 16) * NC;         // 1024
    jeffress_kernel<<<nblocks, 256, 0, stream>>>(ws, weight, delay, (float4*)out);
}